// Round 12
// baseline (154.094 us; speedup 1.0000x reference)
//
#include <hip/hip_runtime.h>
#include <hip/hip_fp16.h>

#define NU 100000
#define NI 200000
#define NF 64
#define NE 1000000
#define NN 300000                 // NU + NI
#define CB 1024                   // rows per coarse bucket
#define NB 293                    // ceil(NN / CB)
#define CAP 4000                  // bucket capacity (mean 3413, sigma 58 -> +10 sigma)
#define P1E 4096                  // edges per pass1 block
#define P1B ((NE + P1E - 1) / P1E)   // 245 pass1 blocks

typedef float nfloat4 __attribute__((ext_vector_type(4)));
typedef unsigned int nuint4 __attribute__((ext_vector_type(4)));

// ---------- fp16 helpers (8 halves in a uint4) ----------
__device__ __forceinline__ void fma8(float sum[8], float v, uint4 q) {
    union { uint4 u; __half2 h[4]; } c; c.u = q;
    #pragma unroll
    for (int i = 0; i < 4; ++i) {
        float2 f = __half22float2(c.h[i]);
        sum[2 * i]     = fmaf(v, f.x, sum[2 * i]);
        sum[2 * i + 1] = fmaf(v, f.y, sum[2 * i + 1]);
    }
}
__device__ __forceinline__ uint4 pack8(const float s[8]) {
    union { uint4 u; __half2 h[4]; } c;
    #pragma unroll
    for (int i = 0; i < 4; ++i)
        c.h[i] = __float22half2_rn(make_float2(s[2 * i], s[2 * i + 1]));
    return c.u;
}
__device__ __forceinline__ void add8(float4& a0, float4& a1, uint4 q) {
    union { uint4 u; __half2 h[4]; } c; c.u = q;
    float2 f0 = __half22float2(c.h[0]);
    float2 f1 = __half22float2(c.h[1]);
    float2 f2 = __half22float2(c.h[2]);
    float2 f3 = __half22float2(c.h[3]);
    a0.x += f0.x; a0.y += f0.y; a0.z += f1.x; a0.w += f1.y;
    a1.x += f2.x; a1.y += f2.y; a1.z += f3.x; a1.w += f3.y;
}
__device__ __forceinline__ uint4 ntload4(const uint4* p) {
    nuint4 v = __builtin_nontemporal_load((const nuint4*)p);
    uint4 r; r.x = v.x; r.y = v.y; r.z = v.z; r.w = v.w; return r;
}

// ---------- 1. pass1: LDS-staged partition + fused fp32->fp16 base-table convert ----------
// record: val(32) << 32 | localrow(10) << 19 | col(19)
__global__ __launch_bounds__(1024) void pass1(const int* __restrict__ rows,
                                              const int* __restrict__ cols,
                                              const float* __restrict__ vals,
                                              int* __restrict__ gcur,
                                              unsigned long long* __restrict__ ebuf,
                                              const float4* __restrict__ user4,
                                              const float4* __restrict__ item4,
                                              uint4* __restrict__ f0h) {
    __shared__ unsigned long long srec[P1E];     // 32 KB
    __shared__ unsigned short     sbuk[P1E];     // 8 KB
    __shared__ int hist[NB], lstart[NB], gbase[NB], lcur[NB];
    __shared__ int wsum[16];
    int t = threadIdx.x;
    for (int i = t; i < NB; i += 1024) hist[i] = 0;
    __syncthreads();

    int e0 = blockIdx.x * P1E;
    int total = NE - e0; if (total > P1E) total = P1E;

    unsigned long long rec[4]; int bk[4];
    #pragma unroll
    for (int i = 0; i < 4; ++i) {
        int e = e0 + i * 1024 + t;
        if (e < NE) {
            int r = rows[e];
            bk[i] = r >> 10;
            rec[i] = ((unsigned long long)(unsigned)__float_as_uint(vals[e]) << 32)
                   | ((unsigned)(r & (CB - 1)) << 19) | (unsigned)cols[e];
            atomicAdd(&hist[bk[i]], 1);
        } else bk[i] = -1;
    }
    __syncthreads();

    // exclusive scan of hist via wave-shuffle scan (2 barriers)
    {
        int v = (t < NB) ? hist[t] : 0;
        int lane = t & 63, wave = t >> 6;
        int inc = v;
        #pragma unroll
        for (int off = 1; off < 64; off <<= 1) {
            int y = __shfl_up(inc, off);
            if (lane >= off) inc += y;
        }
        if (lane == 63) wsum[wave] = inc;
        __syncthreads();
        if (t < 16) {
            int w = wsum[t];
            #pragma unroll
            for (int off = 1; off < 16; off <<= 1) {
                int y = __shfl_up(w, off);
                if (t >= off) w += y;
            }
            wsum[t] = w;
        }
        __syncthreads();
        int excl = ((wave > 0) ? wsum[wave - 1] : 0) + inc - v;
        if (t < NB) {
            lstart[t] = excl;
            lcur[t] = excl;
            gbase[t] = (v > 0) ? atomicAdd(&gcur[t * 16], v) : 0;   // hot-line reserve
        }
    }
    __syncthreads();

    // LDS counting-sort by bucket
    #pragma unroll
    for (int i = 0; i < 4; ++i) {
        if (bk[i] >= 0) {
            int p = atomicAdd(&lcur[bk[i]], 1);
            srec[p] = rec[i];
            sbuk[p] = (unsigned short)bk[i];
        }
    }
    __syncthreads();

    // stream out: contiguous runs per bucket
    for (int i = t; i < total; i += 1024) {
        int b = sbuk[i];
        int off = gbase[b] + (i - lstart[b]);
        if (off < CAP) ebuf[(size_t)b * CAP + off] = srec[i];
    }

    // fused fp32 -> fp16 base-table conversion (grid-stride tail)
    const size_t ub = (size_t)NU * 16;
    for (int i = blockIdx.x * 1024 + t; i < NN * 8; i += P1B * 1024) {
        size_t fi = (size_t)i * 2;
        float4 a = (fi < ub) ? user4[fi] : item4[fi - ub];
        float4 b = (fi + 1 < ub) ? user4[fi + 1] : item4[fi + 1 - ub];
        float s[8] = { a.x, a.y, a.z, a.w, b.x, b.y, b.z, b.w };
        f0h[i] = pack8(s);
    }
}

// ---------- 2. pass2: per-bucket LDS counting-sort by row; emit packed (start|cnt) ----------
// No srec staging (re-read L2/L3-hot ebuf), wave-shuffle scan -> 40 KB LDS, few barriers.
__global__ __launch_bounds__(1024) void pass2(const int* __restrict__ gcur,
                                              unsigned long long* __restrict__ ebuf,
                                              int* __restrict__ rinfo) {
    __shared__ unsigned long long srt2[CAP];     // 32 KB
    __shared__ int hist[CB];                     // 4 KB
    __shared__ int lcur[CB];                     // 4 KB
    __shared__ int wsum[16];
    int b = blockIdx.x, t = threadIdx.x;
    int cnt = gcur[b * 16]; if (cnt > CAP) cnt = CAP;
    const size_t base = (size_t)b * CAP;

    hist[t] = 0;
    __syncthreads();
    for (int i = t; i < cnt; i += 1024)
        atomicAdd(&hist[((unsigned)(unsigned long long)ebuf[base + i] >> 19) & (CB - 1)], 1);
    __syncthreads();

    int v = hist[t];
    int lane = t & 63, wave = t >> 6;
    int inc = v;
    #pragma unroll
    for (int off = 1; off < 64; off <<= 1) {
        int y = __shfl_up(inc, off);
        if (lane >= off) inc += y;
    }
    if (lane == 63) wsum[wave] = inc;
    __syncthreads();
    if (t < 16) {
        int w = wsum[t];
        #pragma unroll
        for (int off = 1; off < 16; off <<= 1) {
            int y = __shfl_up(w, off);
            if (t >= off) w += y;
        }
        wsum[t] = w;
    }
    __syncthreads();
    int excl = ((wave > 0) ? wsum[wave - 1] : 0) + inc - v;

    int rc = v; if (rc > 127) rc = 127;
    int row = b * CB + t;
    if (row < NN) rinfo[row] = ((int)base + excl) | (rc << 25);  // start:25 | cnt:7
    lcur[t] = excl;
    __syncthreads();
    // counting-sort into LDS (second global read, L2-hot)
    for (int i = t; i < cnt; i += 1024) {
        unsigned long long r = ebuf[base + i];
        int p = atomicAdd(&lcur[((unsigned)r >> 19) & (CB - 1)], 1);
        srt2[p] = r;
    }
    __syncthreads();
    // coalesced write-back in place
    for (int i = t; i < cnt; i += 1024) ebuf[base + i] = srt2[i];
}

// ---------- 3. SpMM: 8 lanes/row, 2-wide edge pairs ----------
// MODE 0/1: write fout (fp16 table) only.
// MODE 2:   acc = f0(fp16) + f1 + f2 + sum   (nontemporal stream epilogue)
template <int MODE>
__global__ void spmm_row8(const int* __restrict__ rinfo,
                          const int2* __restrict__ edges, const uint4* __restrict__ gtab,
                          uint4* __restrict__ fout,
                          const uint4* __restrict__ f0h, const uint4* __restrict__ f1h,
                          const uint4* __restrict__ f2h,
                          float4* __restrict__ acc) {
    int tid = blockIdx.x * blockDim.x + threadIdx.x;
    int row = tid >> 3;          // 8 rows per wave
    if (row >= NN) return;
    int j = tid & 7;             // 16B chunk (8 feats) of the row
    int ri = rinfo[row];
    int s = ri & 0x1FFFFFF;
    int e = s + ((unsigned)ri >> 25);
    float sum[8], sumB[8];
    #pragma unroll
    for (int t = 0; t < 8; ++t) { sum[t] = 0.f; sumB[t] = 0.f; }

    int k = s;
    while (k + 1 < e) {
        int2 d0 = edges[k];
        int2 d1 = edges[k + 1];
        uint4 q0 = gtab[(size_t)(d0.x & 0x7FFFF) * 8 + j];   // independent pair
        uint4 q1 = gtab[(size_t)(d1.x & 0x7FFFF) * 8 + j];   // of 128B gathers
        fma8(sum,  __int_as_float(d0.y), q0);
        fma8(sumB, __int_as_float(d1.y), q1);
        k += 2;
    }
    if (k < e) {
        int2 d0 = edges[k];
        uint4 q0 = gtab[(size_t)(d0.x & 0x7FFFF) * 8 + j];
        fma8(sum, __int_as_float(d0.y), q0);
    }
    #pragma unroll
    for (int t = 0; t < 8; ++t) sum[t] += sumB[t];

    if (MODE != 2) {
        fout[(size_t)row * 8 + j] = pack8(sum);
    } else {
        size_t t8 = (size_t)row * 8 + j;
        float4 a0 = make_float4(sum[0], sum[1], sum[2], sum[3]);
        float4 a1 = make_float4(sum[4], sum[5], sum[6], sum[7]);
        add8(a0, a1, ntload4(&f0h[t8]));      // read-once streams: don't pollute L2
        add8(a0, a1, ntload4(&f1h[t8]));
        add8(a0, a1, ntload4(&f2h[t8]));
        size_t r16 = (size_t)row * 16 + (size_t)j * 2;
        nfloat4 n0 = { a0.x, a0.y, a0.z, a0.w };
        nfloat4 n1 = { a1.x, a1.y, a1.z, a1.w };
        __builtin_nontemporal_store(n0, (nfloat4*)&acc[r16]);
        __builtin_nontemporal_store(n1, (nfloat4*)&acc[r16 + 1]);
    }
}

extern "C" void kernel_launch(void* const* d_in, const int* in_sizes, int n_in,
                              void* d_out, int out_size, void* d_ws, size_t ws_size,
                              hipStream_t stream) {
    const float* user = (const float*)d_in[0];
    const float* item = (const float*)d_in[1];
    const int*   rows = (const int*)d_in[2];
    const int*   cols = (const int*)d_in[3];
    const float* vals = (const float*)d_in[4];
    float* acc = (float*)d_out;

    const size_t TB = (size_t)NN * 8 * sizeof(uint4);    // fp16 table: 38.4 MB
    char* w = (char*)d_ws;
    uint4* f0h = (uint4*)(w);
    uint4* f1h = (uint4*)(w + TB);
    uint4* f2h = (uint4*)(w + 2 * TB);
    unsigned long long* ebuf = (unsigned long long*)(w + 3 * TB);
    char* w2 = w + 3 * TB + (size_t)NB * CAP * 8;        // after 9.4 MB ebuf
    int* gcur  = (int*)(w2);                             // NB*16 ints
    int* rinfo = (int*)(w2 + (size_t)NB * 16 * 4);       // NN ints

    const int blocksR = NN * 8 / 256;            // 9375

    (void)hipMemsetAsync(gcur, 0, (size_t)NB * 16 * sizeof(int), stream);
    pass1<<<P1B, 1024, 0, stream>>>(rows, cols, vals, gcur, ebuf,
                                    (const float4*)user, (const float4*)item, f0h);
    pass2<<<NB, 1024, 0, stream>>>(gcur, ebuf, rinfo);

    spmm_row8<0><<<blocksR, 256, 0, stream>>>(rinfo, (const int2*)ebuf, f0h,
                                              f1h, nullptr, nullptr, nullptr, nullptr);
    spmm_row8<1><<<blocksR, 256, 0, stream>>>(rinfo, (const int2*)ebuf, f1h,
                                              f2h, nullptr, nullptr, nullptr, nullptr);
    spmm_row8<2><<<blocksR, 256, 0, stream>>>(rinfo, (const int2*)ebuf, f2h,
                                              nullptr, f0h, f1h, f2h,
                                              (float4*)acc);
}

// Round 13
// 152.539 us; speedup vs baseline: 1.0102x; 1.0102x over previous
//
#include <hip/hip_runtime.h>
#include <hip/hip_fp16.h>

#define NU 100000
#define NI 200000
#define NF 64
#define NE 1000000
#define NN 300000                 // NU + NI
#define CB 1024                   // rows per coarse bucket
#define NB 293                    // ceil(NN / CB)
#define CAP 4000                  // bucket capacity (mean 3413, sigma 58 -> +10 sigma)
#define P1E 4096                  // edges per pass1 block
#define P1B ((NE + P1E - 1) / P1E)   // 245 pass1 blocks

typedef float nfloat4 __attribute__((ext_vector_type(4)));

// ---------- fp16 helpers (8 halves in a uint4) ----------
__device__ __forceinline__ void fma8(float sum[8], float v, uint4 q) {
    union { uint4 u; __half2 h[4]; } c; c.u = q;
    #pragma unroll
    for (int i = 0; i < 4; ++i) {
        float2 f = __half22float2(c.h[i]);
        sum[2 * i]     = fmaf(v, f.x, sum[2 * i]);
        sum[2 * i + 1] = fmaf(v, f.y, sum[2 * i + 1]);
    }
}
__device__ __forceinline__ uint4 pack8(const float s[8]) {
    union { uint4 u; __half2 h[4]; } c;
    #pragma unroll
    for (int i = 0; i < 4; ++i)
        c.h[i] = __float22half2_rn(make_float2(s[2 * i], s[2 * i + 1]));
    return c.u;
}
__device__ __forceinline__ void add8(float4& a0, float4& a1, uint4 q) {
    union { uint4 u; __half2 h[4]; } c; c.u = q;
    float2 f0 = __half22float2(c.h[0]);
    float2 f1 = __half22float2(c.h[1]);
    float2 f2 = __half22float2(c.h[2]);
    float2 f3 = __half22float2(c.h[3]);
    a0.x += f0.x; a0.y += f0.y; a0.z += f1.x; a0.w += f1.y;
    a1.x += f2.x; a1.y += f2.y; a1.z += f3.x; a1.w += f3.y;
}

// ---------- 1. pass1: LDS-staged partition + fused fp32->fp16 base-table convert ----------
// record: val(32) << 32 | localrow(10) << 19 | col(19)
__global__ __launch_bounds__(1024) void pass1(const int* __restrict__ rows,
                                              const int* __restrict__ cols,
                                              const float* __restrict__ vals,
                                              int* __restrict__ gcur,
                                              unsigned long long* __restrict__ ebuf,
                                              const float4* __restrict__ user4,
                                              const float4* __restrict__ item4,
                                              uint4* __restrict__ f0h) {
    __shared__ unsigned long long srec[P1E];     // 32 KB
    __shared__ unsigned short     sbuk[P1E];     // 8 KB
    __shared__ int hist[NB], lstart[NB], gbase[NB], lcur[NB];
    __shared__ int wsum[16];
    int t = threadIdx.x;
    for (int i = t; i < NB; i += 1024) hist[i] = 0;
    __syncthreads();

    int e0 = blockIdx.x * P1E;
    int total = NE - e0; if (total > P1E) total = P1E;

    unsigned long long rec[4]; int bk[4];
    #pragma unroll
    for (int i = 0; i < 4; ++i) {
        int e = e0 + i * 1024 + t;
        if (e < NE) {
            int r = rows[e];
            bk[i] = r >> 10;
            rec[i] = ((unsigned long long)(unsigned)__float_as_uint(vals[e]) << 32)
                   | ((unsigned)(r & (CB - 1)) << 19) | (unsigned)cols[e];
            atomicAdd(&hist[bk[i]], 1);
        } else bk[i] = -1;
    }
    __syncthreads();

    // exclusive scan of hist via wave-shuffle scan (2 barriers)
    {
        int v = (t < NB) ? hist[t] : 0;
        int lane = t & 63, wave = t >> 6;
        int inc = v;
        #pragma unroll
        for (int off = 1; off < 64; off <<= 1) {
            int y = __shfl_up(inc, off);
            if (lane >= off) inc += y;
        }
        if (lane == 63) wsum[wave] = inc;
        __syncthreads();
        if (t < 16) {
            int w = wsum[t];
            #pragma unroll
            for (int off = 1; off < 16; off <<= 1) {
                int y = __shfl_up(w, off);
                if (t >= off) w += y;
            }
            wsum[t] = w;
        }
        __syncthreads();
        int excl = ((wave > 0) ? wsum[wave - 1] : 0) + inc - v;
        if (t < NB) {
            lstart[t] = excl;
            lcur[t] = excl;
            gbase[t] = (v > 0) ? atomicAdd(&gcur[t * 16], v) : 0;   // hot-line reserve
        }
    }
    __syncthreads();

    // LDS counting-sort by bucket
    #pragma unroll
    for (int i = 0; i < 4; ++i) {
        if (bk[i] >= 0) {
            int p = atomicAdd(&lcur[bk[i]], 1);
            srec[p] = rec[i];
            sbuk[p] = (unsigned short)bk[i];
        }
    }
    __syncthreads();

    // stream out: contiguous runs per bucket
    for (int i = t; i < total; i += 1024) {
        int b = sbuk[i];
        int off = gbase[b] + (i - lstart[b]);
        if (off < CAP) ebuf[(size_t)b * CAP + off] = srec[i];
    }

    // fused fp32 -> fp16 base-table conversion (grid-stride tail)
    const size_t ub = (size_t)NU * 16;
    for (int i = blockIdx.x * 1024 + t; i < NN * 8; i += P1B * 1024) {
        size_t fi = (size_t)i * 2;
        float4 a = (fi < ub) ? user4[fi] : item4[fi - ub];
        float4 b = (fi + 1 < ub) ? user4[fi + 1] : item4[fi + 1 - ub];
        float s[8] = { a.x, a.y, a.z, a.w, b.x, b.y, b.z, b.w };
        f0h[i] = pack8(s);
    }
}

// ---------- 2. pass2: per-bucket LDS counting-sort by row; emit packed (start|cnt) ----------
__global__ __launch_bounds__(1024) void pass2(const int* __restrict__ gcur,
                                              unsigned long long* __restrict__ ebuf,
                                              int* __restrict__ rinfo) {
    __shared__ unsigned long long srt2[CAP];     // 32 KB
    __shared__ int hist[CB];                     // 4 KB
    __shared__ int lcur[CB];                     // 4 KB
    __shared__ int wsum[16];
    int b = blockIdx.x, t = threadIdx.x;
    int cnt = gcur[b * 16]; if (cnt > CAP) cnt = CAP;
    const size_t base = (size_t)b * CAP;

    hist[t] = 0;
    __syncthreads();
    for (int i = t; i < cnt; i += 1024)
        atomicAdd(&hist[((unsigned)(unsigned long long)ebuf[base + i] >> 19) & (CB - 1)], 1);
    __syncthreads();

    int v = hist[t];
    int lane = t & 63, wave = t >> 6;
    int inc = v;
    #pragma unroll
    for (int off = 1; off < 64; off <<= 1) {
        int y = __shfl_up(inc, off);
        if (lane >= off) inc += y;
    }
    if (lane == 63) wsum[wave] = inc;
    __syncthreads();
    if (t < 16) {
        int w = wsum[t];
        #pragma unroll
        for (int off = 1; off < 16; off <<= 1) {
            int y = __shfl_up(w, off);
            if (t >= off) w += y;
        }
        wsum[t] = w;
    }
    __syncthreads();
    int excl = ((wave > 0) ? wsum[wave - 1] : 0) + inc - v;

    int rc = v; if (rc > 127) rc = 127;
    int row = b * CB + t;
    if (row < NN) rinfo[row] = ((int)base + excl) | (rc << 25);  // start:25 | cnt:7
    lcur[t] = excl;
    __syncthreads();
    // counting-sort into LDS (second global read, L2-hot)
    for (int i = t; i < cnt; i += 1024) {
        unsigned long long r = ebuf[base + i];
        int p = atomicAdd(&lcur[((unsigned)r >> 19) & (CB - 1)], 1);
        srt2[p] = r;
    }
    __syncthreads();
    // coalesced write-back in place
    for (int i = t; i < cnt; i += 1024) ebuf[base + i] = srt2[i];
}

// ---------- 3. SpMM: 8 lanes/row, 2-wide edge pairs ----------
// MODE 0/1: write fout (fp16 table) only.
// MODE 2:   acc = f0(fp16) + f1 + f2 + sum   (cached loads, nt stores)
template <int MODE>
__global__ void spmm_row8(const int* __restrict__ rinfo,
                          const int2* __restrict__ edges, const uint4* __restrict__ gtab,
                          uint4* __restrict__ fout,
                          const uint4* __restrict__ f0h, const uint4* __restrict__ f1h,
                          const uint4* __restrict__ f2h,
                          float4* __restrict__ acc) {
    int tid = blockIdx.x * blockDim.x + threadIdx.x;
    int row = tid >> 3;          // 8 rows per wave
    if (row >= NN) return;
    int j = tid & 7;             // 16B chunk (8 feats) of the row
    int ri = rinfo[row];
    int s = ri & 0x1FFFFFF;
    int e = s + ((unsigned)ri >> 25);
    float sum[8], sumB[8];
    #pragma unroll
    for (int t = 0; t < 8; ++t) { sum[t] = 0.f; sumB[t] = 0.f; }

    int k = s;
    while (k + 1 < e) {
        int2 d0 = edges[k];
        int2 d1 = edges[k + 1];
        uint4 q0 = gtab[(size_t)(d0.x & 0x7FFFF) * 8 + j];   // independent pair
        uint4 q1 = gtab[(size_t)(d1.x & 0x7FFFF) * 8 + j];   // of 128B gathers
        fma8(sum,  __int_as_float(d0.y), q0);
        fma8(sumB, __int_as_float(d1.y), q1);
        k += 2;
    }
    if (k < e) {
        int2 d0 = edges[k];
        uint4 q0 = gtab[(size_t)(d0.x & 0x7FFFF) * 8 + j];
        fma8(sum, __int_as_float(d0.y), q0);
    }
    #pragma unroll
    for (int t = 0; t < 8; ++t) sum[t] += sumB[t];

    if (MODE != 2) {
        fout[(size_t)row * 8 + j] = pack8(sum);
    } else {
        size_t t8 = (size_t)row * 8 + j;
        float4 a0 = make_float4(sum[0], sum[1], sum[2], sum[3]);
        float4 a1 = make_float4(sum[4], sum[5], sum[6], sum[7]);
        add8(a0, a1, f0h[t8]);
        add8(a0, a1, f1h[t8]);
        add8(a0, a1, f2h[t8]);
        size_t r16 = (size_t)row * 16 + (size_t)j * 2;
        nfloat4 n0 = { a0.x, a0.y, a0.z, a0.w };
        nfloat4 n1 = { a1.x, a1.y, a1.z, a1.w };
        __builtin_nontemporal_store(n0, (nfloat4*)&acc[r16]);
        __builtin_nontemporal_store(n1, (nfloat4*)&acc[r16 + 1]);
    }
}

extern "C" void kernel_launch(void* const* d_in, const int* in_sizes, int n_in,
                              void* d_out, int out_size, void* d_ws, size_t ws_size,
                              hipStream_t stream) {
    const float* user = (const float*)d_in[0];
    const float* item = (const float*)d_in[1];
    const int*   rows = (const int*)d_in[2];
    const int*   cols = (const int*)d_in[3];
    const float* vals = (const float*)d_in[4];
    float* acc = (float*)d_out;

    const size_t TB = (size_t)NN * 8 * sizeof(uint4);    // fp16 table: 38.4 MB
    char* w = (char*)d_ws;
    uint4* f0h = (uint4*)(w);
    uint4* f1h = (uint4*)(w + TB);
    uint4* f2h = (uint4*)(w + 2 * TB);
    unsigned long long* ebuf = (unsigned long long*)(w + 3 * TB);
    char* w2 = w + 3 * TB + (size_t)NB * CAP * 8;        // after 9.4 MB ebuf
    int* gcur  = (int*)(w2);                             // NB*16 ints
    int* rinfo = (int*)(w2 + (size_t)NB * 16 * 4);       // NN ints

    const int blocksR = NN * 8 / 256;            // 9375

    (void)hipMemsetAsync(gcur, 0, (size_t)NB * 16 * sizeof(int), stream);
    pass1<<<P1B, 1024, 0, stream>>>(rows, cols, vals, gcur, ebuf,
                                    (const float4*)user, (const float4*)item, f0h);
    pass2<<<NB, 1024, 0, stream>>>(gcur, ebuf, rinfo);

    spmm_row8<0><<<blocksR, 256, 0, stream>>>(rinfo, (const int2*)ebuf, f0h,
                                              f1h, nullptr, nullptr, nullptr, nullptr);
    spmm_row8<1><<<blocksR, 256, 0, stream>>>(rinfo, (const int2*)ebuf, f1h,
                                              f2h, nullptr, nullptr, nullptr, nullptr);
    spmm_row8<2><<<blocksR, 256, 0, stream>>>(rinfo, (const int2*)ebuf, f2h,
                                              nullptr, f0h, f1h, f2h,
                                              (float4*)acc);
}